// Round 12
// baseline (365.515 us; speedup 1.0000x reference)
//
#include <hip/hip_runtime.h>
#include <math.h>

// HiddenLayer_20126216749058: sparse-GP layer, N=1024, Q=32, M=256, D=32.
// R12 = R11 (≈R7 best, 179-180us) restructured 5 launches -> 4:
//   - NS moved into kA: E-tiles computed inline from Z (recompute exps, ~1M,
//     trivial) so NS no longer depends on kA's KM writes. Kinv/Kh ready at kA end.
//   - abf + t3 moved into kB.
//   - W1->W chain replaced by ONE fused 8-block segment in kF (M=Kinv@psi2s in
//     LDS, then W=M@Kinv, trace vs (Scov+qq) folded inline; W never stored).
//   - kD eliminated. Hot loops (psi2, tmp, scov, GA, fvar) byte-identical.

#define N_PTS 1024
#define QD 32
#define MI 256
#define DOUT 32
#define JITTER 1e-6f
#define LOG2E 1.4426950408889634f
#define LSU 40    // bf16 LDS row stride (80B)

typedef short short8 __attribute__((ext_vector_type(8)));
typedef float floatx4 __attribute__((ext_vector_type(4)));
typedef unsigned short ushort;

// ---- workspace layout (float offsets) ----
#define OFF_PSI2S 0           // 65536 zeroed (atomic)
#define OFF_SCOV  65536       // 65536 zeroed (atomic)
#define OFF_GA    131072      // 65536 zeroed (atomic)
#define OFF_S     196608      // 16 scalars zeroed; [8] = done-counter
#define ZERO_CNT  196624
#define OFF_PSI1  196624      // 262144 N*M fp32
#define OFF_P1H   458768      // 131072 N*M bf16
#define OFF_GM    589840      // 262144 N*M fp32 (LOG2E-scaled)
#define OFF_F2    851984      // 32768  N*Q fp32 (LOG2E-scaled)
#define OFF_KM    884752      // 65536
#define OFF_KINV  950288      // 65536
#define OFF_KH    1015824     // 32768  M*M bf16
#define OFF_T3    1048592     // 8192   M*D
#define OFF_ZB    1056784     // 4096   M*Q bf16
#define OFF_ABF   1060880     // 131072 N*M bf16
#define OFF_ABFT  1191952     // 131072 M*N bf16
#define OFF_BTJ   1323024     // 1048576 D*M*M bf16 [d][j][l]
#define OFF_BTL   2371600     // 1048576 D*M*M bf16 [d][l][j]
#define OFF_TMP   3420176     // 4194304 N*D*M bf16 [n][d][l]
// end = 7614480 floats = 30.5 MB

struct Params {
  const float *Xm, *Xv, *Z, *ls, *pvar, *pbeta, *qmu, *qs;
  float *psi1, *gm, *f2, *KM, *Kinv, *t3;
  float *psi2s, *Scov, *GA, *Sv, *zarea;
  ushort *p1h, *Kh, *zb, *abf, *abfT, *Btj, *Btl, *tmp;
  float *outMean, *outVar, *outL;
};

__device__ __forceinline__ ushort f2bf(float x) {
  unsigned int u = __builtin_bit_cast(unsigned int, x);
  u += 0x7fffu + ((u >> 16) & 1u);
  return (ushort)(u >> 16);
}

__device__ __forceinline__ void finalize_check(const Params& p) {
  // caller: tid==0, after its Sv atomicAdd
  __threadfence();
  unsigned prev = atomicAdd((unsigned int*)&p.Sv[8], 1u);
  if (prev == 199u) {   // 192 reducers + 8 Wfused
    float S0 = atomicAdd(&p.Sv[0], 0.f);
    float S1 = atomicAdd(&p.Sv[1], 0.f);
    float S2 = atomicAdd(&p.Sv[2], 0.f);
    float S4 = atomicAdd(&p.Sv[4], 0.f);
    float S5 = atomicAdd(&p.Sv[5], 0.f);
    float S6 = atomicAdd(&p.Sv[6], 0.f);
    float S7 = atomicAdd(&p.Sv[7], 0.f);
    float v = *p.pvar, b = *p.pbeta;
    float trace = (float)N_PTS * v - S0;
    float lml = -0.5f * b * (float)DOUT * trace;
    float c = v + JITTER;
    float logdetK = (float)MI * logf(c) - 0.5f * S4;
    float kl = 0.5f*(S1 + S2 - (float)(MI*DOUT) + (float)DOUT*logdetK - S5);
    lml -= kl;
    lml -= 0.5f * b * (S6 - S7);
    p.outL[0] = lml;
  }
}

#define BLOCK_FOLD_FIN(s_, red_, pp_, tgt_)                              \
  { float sv_ = (s_);                                                    \
    _Pragma("unroll")                                                    \
    for (int off_ = 32; off_ >= 1; off_ >>= 1) sv_ += __shfl_down(sv_, off_, 64); \
    if ((threadIdx.x & 63) == 0) red_[threadIdx.x >> 6] = sv_;           \
    __syncthreads();                                                     \
    if (threadIdx.x == 0) {                                              \
      atomicAdd(&(pp_).Sv[tgt_], red_[0]+red_[1]+red_[2]+red_[3]);       \
      finalize_check(pp_);                                               \
    } }

// ================= Phase A =================
// [0,1024) stats | [1024,1280) KM | [1280,1377) zero | [1377,1385) zb
// [1385,2409) btj | [2409,3433) btl | [3433,3497) NS (inline-Z E-tiles)
__global__ __launch_bounds__(256) void kA(Params p) {
  __shared__ __align__(16) float sb[4288];
  int bx = blockIdx.x, tid = threadIdx.x;
  if (bx < N_PTS) {
    int n = bx;
    float* w1s = sb; float* w1mu = sb+32; float* w2s = sb+64; float* w2mu = sb+96;
    float* rl2s = sb+128; float* la1 = sb+160; float* a1s = sb+192;
    float* la2 = sb+224; float* a2s = sb+256;
    float v = *p.pvar;
    if (tid < QD) {
      int q = tid;
      float s = p.Xv[n*QD+q], mu = p.Xm[n*QD+q], l = p.ls[q], l2 = l*l;
      float rl2 = 1.f/l2;
      float d1 = l2 + s, d2 = l2 + 2.f*s;
      float iw1 = 1.f/d1, iw2 = 1.f/d2;
      w1s[q] = iw1; w1mu[q] = iw1*mu; w2s[q] = iw2; w2mu[q] = iw2*mu; rl2s[q] = rl2;
      la1[q] = logf(d1*rl2); a1s[q] = mu*mu*iw1;
      la2[q] = logf(d2*rl2); a2s[q] = mu*mu*iw2;
      p.f2[n*QD+q] = LOG2E*0.5f*(rl2 - iw2);
    }
    __syncthreads();
    if (tid == 0) {
      float s1=0, s2=0, s3=0, s4=0;
      for (int q = 0; q < QD; q++) { s1 += la1[q]; s2 += a1s[q]; s3 += la2[q]; s4 += a2s[q]; }
      sb[288] = -0.5f*(s1 + s2);
      sb[289] = 2.f*logf(v) - 0.5f*s3 - s4;
    }
    __syncthreads();
    float c1sh = sb[288], c2sh = sb[289];
    int m = tid;
    float b1 = 0, c1a = 0, eb = 0, ec = 0, zsq = 0;
    #pragma unroll
    for (int q4 = 0; q4 < QD; q4 += 4) {
      float4 z4 = *(const float4*)&p.Z[m*QD + q4];
      float z, zz;
      z = z4.x; zz = z*z; b1 += w1mu[q4+0]*z; c1a += w1s[q4+0]*zz; eb += w2mu[q4+0]*z; ec += w2s[q4+0]*zz; zsq += rl2s[q4+0]*zz;
      z = z4.y; zz = z*z; b1 += w1mu[q4+1]*z; c1a += w1s[q4+1]*zz; eb += w2mu[q4+1]*z; ec += w2s[q4+1]*zz; zsq += rl2s[q4+1]*zz;
      z = z4.z; zz = z*z; b1 += w1mu[q4+2]*z; c1a += w1s[q4+2]*zz; eb += w2mu[q4+2]*z; ec += w2s[q4+2]*zz; zsq += rl2s[q4+2]*zz;
      z = z4.w; zz = z*z; b1 += w1mu[q4+3]*z; c1a += w1s[q4+3]*zz; eb += w2mu[q4+3]*z; ec += w2s[q4+3]*zz; zsq += rl2s[q4+3]*zz;
    }
    float pv = v * __expf(c1sh + b1 - 0.5f*c1a);
    p.psi1[n*MI + m] = pv;
    p.p1h[n*MI + m] = f2bf(pv);
    p.gm[n*MI + m] = LOG2E*(0.5f*c2sh + (eb - 0.25f*ec) - 0.25f*zsq);
  } else if (bx < N_PTS + MI) {
    int m = bx - N_PTS;
    if (tid < QD) { float l = p.ls[tid]; sb[tid] = 1.f/(l*l); }
    __syncthreads();
    int k = tid;
    float acc = 0;
    #pragma unroll
    for (int q4 = 0; q4 < QD; q4 += 4) {
      float4 zm = *(const float4*)&p.Z[m*QD + q4];
      float4 zk = *(const float4*)&p.Z[k*QD + q4];
      float d;
      d = zm.x - zk.x; acc += d*d*sb[q4+0];
      d = zm.y - zk.y; acc += d*d*sb[q4+1];
      d = zm.z - zk.z; acc += d*d*sb[q4+2];
      d = zm.w - zk.w; acc += d*d*sb[q4+3];
    }
    float v = *p.pvar;
    p.KM[m*MI + k] = v*__expf(-0.5f*acc) + (m == k ? JITTER : 0.f);
  } else if (bx < 1377) {
    int base = (bx - 1280)*2048 + tid*8;
    #pragma unroll
    for (int e = 0; e < 8; e++) {
      int i = base + e;
      if (i < ZERO_CNT) p.zarea[i] = 0.f;
    }
  } else if (bx < 1385) {
    int i = ((bx - 1377)*256 + tid)*4;
    float4 z = *(const float4*)&p.Z[i];
    uint2 o;
    o.x = (unsigned)f2bf(z.x) | ((unsigned)f2bf(z.y) << 16);
    o.y = (unsigned)f2bf(z.z) | ((unsigned)f2bf(z.w) << 16);
    *(uint2*)&p.zb[i] = o;
  } else if (bx < 2409) {
    // btj: Btj[d][j][l] = (l<=j) ? qs[j,l,d] : 0
    int idx = bx - 1385;
    int j = idx & 255, l0 = (idx >> 8)*64;
    int base = j*8192 + l0*32;
    #pragma unroll
    for (int e = 0; e < 8; e++) {
      int lin = e*256 + tid;
      sb[(lin >> 5)*33 + (lin & 31)] = p.qs[base + lin];
    }
    __syncthreads();
    int ll = tid & 63, kq = tid >> 6;
    int l = l0 + ll;
    #pragma unroll
    for (int w8 = 0; w8 < 8; w8++) {
      int k = kq*8 + w8;
      float v = (l <= j) ? sb[ll*33 + k] : 0.f;
      p.Btj[k*65536 + j*256 + l] = f2bf(v);
    }
  } else if (bx < 3433) {
    int idx = bx - 2409;
    int l = idx & 255, j0 = (idx >> 8)*64;
    {
      int jr = tid >> 2, d8 = (tid & 3)*8;
      const float* src = &p.qs[(j0+jr)*8192 + l*32 + d8];
      float4 a = *(const float4*)src, b = *(const float4*)(src+4);
      float* dst = &sb[jr*33 + d8];
      dst[0]=a.x; dst[1]=a.y; dst[2]=a.z; dst[3]=a.w;
      dst[4]=b.x; dst[5]=b.y; dst[6]=b.z; dst[7]=b.w;
    }
    __syncthreads();
    int d = tid >> 3, j8 = (tid & 7)*8;
    unsigned int pk[4];
    #pragma unroll
    for (int q = 0; q < 4; q++) {
      int ja = j0 + j8 + q*2;
      float va = (l <= ja)   ? sb[(j8 + q*2)*33 + d]     : 0.f;
      float vb = (l <= ja+1) ? sb[(j8 + q*2 + 1)*33 + d] : 0.f;
      pk[q] = (unsigned)f2bf(va) | ((unsigned)f2bf(vb) << 16);
    }
    *(uint4*)&p.Btl[d*65536 + l*256 + j0 + j8] = make_uint4(pk[0], pk[1], pk[2], pk[3]);
  } else {
    // NS: G = E@E with E-tiles computed inline from Z; Kinv = s(2I - sKM + G)
    int idx = bx - 3433;
    int col0 = (idx & 7)*32, row0 = (idx >> 3)*32;
    float v = p.pvar[0];
    float s = 1.f/(v + JITTER);
    float* Zr  = sb;            // [32][33] rows row0..
    float* Zc  = sb + 1056;     // [32][33] rows col0..
    float* As  = sb + 2112;     // [32][33] E_A k-major
    float* Bs  = sb + 3168;     // [32][33]
    float* rl2 = sb + 4224;     // [32]
    {
      int rr = tid >> 3, q4 = (tid & 7)*4;
      *(float4*)&Zr[rr*33 + q4] = *(const float4*)&p.Z[(row0+rr)*32 + q4];
      *(float4*)&Zc[rr*33 + q4] = *(const float4*)&p.Z[(col0+rr)*32 + q4];
      if (tid < 32) { float l = p.ls[tid]; rl2[tid] = 1.f/(l*l); }
    }
    __syncthreads();
    int r2 = (tid >> 4)*2, c2 = (tid & 15)*2;
    float a00=0, a01=0, a10=0, a11=0;
    int sr = tid >> 3, sq = (tid & 7)*4;
    for (int kc = 0; kc < 256; kc += 32) {
      #pragma unroll
      for (int j = 0; j < 4; j++) {
        int c = kc + sq + j;
        const float* zcp = &p.Z[c*32];
        float d = 0;
        #pragma unroll
        for (int q4i = 0; q4i < 32; q4i += 4) {
          float4 z4 = *(const float4*)&zcp[q4i];
          float t;
          t = Zr[sr*33+q4i+0]-z4.x; d += t*t*rl2[q4i+0];
          t = Zr[sr*33+q4i+1]-z4.y; d += t*t*rl2[q4i+1];
          t = Zr[sr*33+q4i+2]-z4.z; d += t*t*rl2[q4i+2];
          t = Zr[sr*33+q4i+3]-z4.w; d += t*t*rl2[q4i+3];
        }
        int ar = row0 + sr;
        float km = v*__expf(-0.5f*d) + (ar == c ? JITTER : 0.f);
        As[(sq+j)*33 + sr] = s*km - (ar == c ? 1.f : 0.f);
      }
      {
        int br = kc + sr;
        const float* zbp = &p.Z[br*32];
        #pragma unroll
        for (int j = 0; j < 4; j++) {
          int cc = col0 + sq + j;
          float d = 0;
          #pragma unroll
          for (int q4i = 0; q4i < 32; q4i += 4) {
            float4 z4 = *(const float4*)&zbp[q4i];
            float t;
            t = z4.x - Zc[(sq+j)*33 + q4i+0]; d += t*t*rl2[q4i+0];
            t = z4.y - Zc[(sq+j)*33 + q4i+1]; d += t*t*rl2[q4i+1];
            t = z4.z - Zc[(sq+j)*33 + q4i+2]; d += t*t*rl2[q4i+2];
            t = z4.w - Zc[(sq+j)*33 + q4i+3]; d += t*t*rl2[q4i+3];
          }
          float km = v*__expf(-0.5f*d) + (br == cc ? JITTER : 0.f);
          Bs[sr*33 + sq + j] = s*km - (br == cc ? 1.f : 0.f);
        }
      }
      __syncthreads();
      #pragma unroll
      for (int kk = 0; kk < 32; kk++) {
        float x0 = As[kk*33 + r2], x1 = As[kk*33 + r2 + 1];
        float y0 = Bs[kk*33 + c2], y1 = Bs[kk*33 + c2 + 1];
        a00 += x0*y0; a01 += x0*y1; a10 += x1*y0; a11 += x1*y1;
      }
      __syncthreads();
    }
    float vals[2][2] = {{a00, a01}, {a10, a11}};
    #pragma unroll
    for (int i = 0; i < 2; i++)
      #pragma unroll
      for (int j = 0; j < 2; j++) {
        int R = row0 + r2 + i, C = col0 + c2 + j;
        float d = 0;
        #pragma unroll
        for (int q = 0; q < 32; q++) {
          float t = Zr[(r2+i)*33 + q] - Zc[(c2+j)*33 + q];
          d += t*t*rl2[q];
        }
        float km = v*__expf(-0.5f*d) + (R == C ? JITTER : 0.f);
        float kv = s*(vals[i][j] + (R == C ? 2.f : 0.f) - s*km);
        p.Kinv[R*MI + C] = kv;
        p.Kh[R*MI + C] = f2bf(kv);
      }
  }
}

// ================= Phase B =================
// [0,1024) psi2 | [1024,1152) scov(Btj) | [1152,1216) abf | [1216,1248) t3
__global__ __launch_bounds__(256) void kB(Params p) {
  __shared__ __align__(16) float sb[2560];
  int bx = blockIdx.x, tid = threadIdx.x;
  int lane = tid & 63, w = tid >> 6, l15 = lane & 15, quad = lane >> 4;
  if (bx < 1024) {
    int tile = bx & 15;
    int tm = (tile & 3)*64, tk = (tile >> 2)*64;
    int n0 = (bx >> 4)*16;
    float zm[8];
    {
      const float* zr = &p.Z[(tm + w*16 + l15)*32 + quad*8];
      float4 aq = *(const float4*)zr, bq = *(const float4*)(zr + 4);
      zm[0]=aq.x; zm[1]=aq.y; zm[2]=aq.z; zm[3]=aq.w;
      zm[4]=bq.x; zm[5]=bq.y; zm[6]=bq.z; zm[7]=bq.w;
    }
    short8 bfr[4];
    #pragma unroll
    for (int c = 0; c < 4; c++)
      bfr[c] = *(const short8*)&p.zb[(tk + c*16 + l15)*32 + quad*8];
    float accs[4][4] = {};
    #pragma unroll 1
    for (int nl = 0; nl < 16; nl++) {
      int n = n0 + nl;
      const float* fp = &p.f2[n*32 + quad*8];
      float4 f0 = *(const float4*)fp, f1 = *(const float4*)(fp + 4);
      unsigned q0 = (unsigned)f2bf(f0.x*zm[0]) | ((unsigned)f2bf(f0.y*zm[1]) << 16);
      unsigned q1 = (unsigned)f2bf(f0.z*zm[2]) | ((unsigned)f2bf(f0.w*zm[3]) << 16);
      unsigned q2 = (unsigned)f2bf(f1.x*zm[4]) | ((unsigned)f2bf(f1.y*zm[5]) << 16);
      unsigned q3 = (unsigned)f2bf(f1.z*zm[6]) | ((unsigned)f2bf(f1.w*zm[7]) << 16);
      uint4 u4 = make_uint4(q0, q1, q2, q3);
      short8 af = __builtin_bit_cast(short8, u4);
      float4 gmv = *(const float4*)&p.gm[n*256 + tm + w*16 + quad*4];
      float gmr[4] = {gmv.x, gmv.y, gmv.z, gmv.w};
      #pragma unroll
      for (int c = 0; c < 4; c++) {
        floatx4 zz = {0.f, 0.f, 0.f, 0.f};
        floatx4 g = __builtin_amdgcn_mfma_f32_16x16x32_bf16(af, bfr[c], zz, 0, 0, 0);
        float gk = p.gm[n*256 + tk + c*16 + l15];
        #pragma unroll
        for (int r = 0; r < 4; r++)
          accs[c][r] += __builtin_exp2f(g[r] + gmr[r] + gk);
      }
    }
    #pragma unroll
    for (int c = 0; c < 4; c++)
      #pragma unroll
      for (int r = 0; r < 4; r++)
        atomicAdd(&p.psi2s[(tm + w*16 + quad*4 + r)*256 + tk + c*16 + l15], accs[c][r]);
  } else if (bx < 1152) {
    int idx = bx - 1024;
    int tile = idx & 15;
    int i0 = (tile & 3)*64, j0 = (tile >> 2)*64;
    int d0 = (idx >> 4)*4;
    ushort* Au = (ushort*)sb; ushort* Bu = Au + 2560;
    floatx4 accs[4];
    #pragma unroll
    for (int c = 0; c < 4; c++) accs[c] = (floatx4){0.f,0.f,0.f,0.f};
    int sr = tid >> 2, sq = (tid & 3)*8;
    for (int dd = 0; dd < 4; dd++) {
      const ushort* base = p.Btj + (size_t)(d0 + dd)*65536;
      for (int kc = 0; kc < 256; kc += 32) {
        __syncthreads();
        *(uint4*)&Au[sr*LSU + sq] = *(const uint4*)&base[(i0+sr)*256 + kc + sq];
        *(uint4*)&Bu[sr*LSU + sq] = *(const uint4*)&base[(j0+sr)*256 + kc + sq];
        __syncthreads();
        short8 af = *(const short8*)&Au[(w*16 + l15)*LSU + quad*8];
        #pragma unroll
        for (int c = 0; c < 4; c++) {
          short8 bfv = *(const short8*)&Bu[(c*16 + l15)*LSU + quad*8];
          accs[c] = __builtin_amdgcn_mfma_f32_16x16x32_bf16(af, bfv, accs[c], 0, 0, 0);
        }
      }
    }
    #pragma unroll
    for (int c = 0; c < 4; c++)
      #pragma unroll
      for (int r = 0; r < 4; r++)
        atomicAdd(&p.Scov[(i0 + w*16 + quad*4 + r)*256 + j0 + c*16 + l15], accs[c][r]);
  } else if (bx < 1216) {
    int idx = bx - 1152;
    int j0 = (idx & 3)*64, n0 = (idx >> 2)*64;
    ushort* Ah = (ushort*)sb; ushort* Bh = Ah + 2560;
    floatx4 acc[4];
    #pragma unroll
    for (int c = 0; c < 4; c++) acc[c] = (floatx4){0.f,0.f,0.f,0.f};
    int sr = tid >> 2, sq = (tid & 3)*8;
    for (int kc = 0; kc < 256; kc += 32) {
      __syncthreads();
      *(uint4*)&Ah[sr*LSU + sq] = *(const uint4*)&p.p1h[(n0+sr)*256 + kc + sq];
      *(uint4*)&Bh[sr*LSU + sq] = *(const uint4*)&p.Kh[(j0+sr)*256 + kc + sq];
      __syncthreads();
      short8 ah = *(const short8*)&Ah[(w*16 + l15)*LSU + quad*8];
      #pragma unroll
      for (int c = 0; c < 4; c++) {
        short8 bh = *(const short8*)&Bh[(c*16 + l15)*LSU + quad*8];
        acc[c] = __builtin_amdgcn_mfma_f32_16x16x32_bf16(ah, bh, acc[c], 0, 0, 0);
      }
    }
    #pragma unroll
    for (int c = 0; c < 4; c++)
      #pragma unroll
      for (int r = 0; r < 4; r++) {
        int n = n0 + w*16 + quad*4 + r, j = j0 + c*16 + l15;
        ushort hv = f2bf(acc[c][r]);
        p.abf[n*256 + j] = hv;
        p.abfT[j*1024 + n] = hv;
      }
  } else {
    int rbase = (bx - 1216)*8;
    int c = tid & 31, r = rbase + (tid >> 5);
    float acc = 0;
    for (int k = 0; k < 256; k += 4) {
      float4 a4 = *(const float4*)&p.Kinv[r*256 + k];
      acc += a4.x*p.qmu[(k+0)*32+c] + a4.y*p.qmu[(k+1)*32+c]
           + a4.z*p.qmu[(k+2)*32+c] + a4.w*p.qmu[(k+3)*32+c];
    }
    p.t3[r*32 + c] = acc;
  }
}

// ================= Phase E =================
// [0,2048) tmp = abf @ BtlFlat^T | [2048,2112) GA gram
__global__ __launch_bounds__(256) void kE(Params p) {
  __shared__ __align__(16) float sb[2560];
  int bx = blockIdx.x, tid = threadIdx.x;
  int lane = tid & 63, w = tid >> 6, l15 = lane & 15, quad = lane >> 4;
  if (bx < 2048) {
    int n0 = (bx & 15)*64;
    int c0 = (bx >> 4)*64;
    ushort* As = (ushort*)sb; ushort* Bs = As + 2560;
    floatx4 acc[4];
    #pragma unroll
    for (int c = 0; c < 4; c++) acc[c] = (floatx4){0.f,0.f,0.f,0.f};
    int sr = tid >> 2, sq = (tid & 3)*8;
    for (int kc = 0; kc < 256; kc += 32) {
      __syncthreads();
      *(uint4*)&As[sr*LSU + sq] = *(const uint4*)&p.abf[(n0+sr)*256 + kc + sq];
      *(uint4*)&Bs[sr*LSU + sq] = *(const uint4*)&p.Btl[(size_t)(c0+sr)*256 + kc + sq];
      __syncthreads();
      short8 af = *(const short8*)&As[(w*16 + l15)*LSU + quad*8];
      #pragma unroll
      for (int c = 0; c < 4; c++) {
        short8 b = *(const short8*)&Bs[(c*16 + l15)*LSU + quad*8];
        acc[c] = __builtin_amdgcn_mfma_f32_16x16x32_bf16(af, b, acc[c], 0, 0, 0);
      }
    }
    #pragma unroll
    for (int c = 0; c < 4; c++)
      #pragma unroll
      for (int r = 0; r < 4; r++) {
        int n = n0 + w*16 + quad*4 + r, cc = c0 + c*16 + l15;
        p.tmp[(size_t)n*8192 + cc] = f2bf(acc[c][r]);
      }
  } else {
    int idx = bx - 2048;
    int tile = idx & 15;
    int i0 = (tile & 3)*64, j0 = (tile >> 2)*64;
    int nc0 = (idx >> 4)*256;
    ushort* Au = (ushort*)sb; ushort* Bu = Au + 2560;
    floatx4 accs[4];
    #pragma unroll
    for (int c = 0; c < 4; c++) accs[c] = (floatx4){0.f,0.f,0.f,0.f};
    int sr = tid >> 2, sq = (tid & 3)*8;
    for (int kc = 0; kc < 256; kc += 32) {
      __syncthreads();
      *(uint4*)&Au[sr*LSU + sq] = *(const uint4*)&p.abfT[(i0+sr)*1024 + nc0 + kc + sq];
      *(uint4*)&Bu[sr*LSU + sq] = *(const uint4*)&p.abfT[(j0+sr)*1024 + nc0 + kc + sq];
      __syncthreads();
      short8 af = *(const short8*)&Au[(w*16 + l15)*LSU + quad*8];
      #pragma unroll
      for (int c = 0; c < 4; c++) {
        short8 bfv = *(const short8*)&Bu[(c*16 + l15)*LSU + quad*8];
        accs[c] = __builtin_amdgcn_mfma_f32_16x16x32_bf16(af, bfv, accs[c], 0, 0, 0);
      }
    }
    #pragma unroll
    for (int c = 0; c < 4; c++)
      #pragma unroll
      for (int r = 0; r < 4; r++)
        atomicAdd(&p.GA[(i0 + w*16 + quad*4 + r)*256 + j0 + c*16 + l15], accs[c][r]);
  }
}

// ================= Phase F =================
// [0,256) fvar | [256,384) mean | [384,392) Wfused (+Sv[6] fold)
// [392,584) reducers (6 segs) ; finalize via counter==200
__global__ __launch_bounds__(256) void kF(Params p) {
  __shared__ __align__(16) float sb[10336];
  __shared__ float red[4];
  int bx = blockIdx.x, tid = threadIdx.x;
  if (bx < 256) {
    int lane = tid & 63, w = tid >> 6;
    int n = bx*4 + w;
    int l15 = lane & 15, quad = lane >> 4;
    floatx4 acc[2][2];
    #pragma unroll
    for (int i = 0; i < 2; i++)
      #pragma unroll
      for (int j = 0; j < 2; j++) acc[i][j] = (floatx4){0.f,0.f,0.f,0.f};
    size_t base = (size_t)n*8192;
    short8 H0[8], H1[8];
    #pragma unroll
    for (int s8 = 0; s8 < 8; s8++) {
      int off = s8*32 + quad*8;
      H0[s8] = *(const short8*)&p.tmp[base + l15*256 + off];
      H1[s8] = *(const short8*)&p.tmp[base + (16 + l15)*256 + off];
    }
    #pragma unroll
    for (int s8 = 0; s8 < 8; s8++) {
      acc[0][0] = __builtin_amdgcn_mfma_f32_16x16x32_bf16(H0[s8], H0[s8], acc[0][0], 0,0,0);
      acc[0][1] = __builtin_amdgcn_mfma_f32_16x16x32_bf16(H0[s8], H1[s8], acc[0][1], 0,0,0);
      acc[1][0] = __builtin_amdgcn_mfma_f32_16x16x32_bf16(H1[s8], H0[s8], acc[1][0], 0,0,0);
      acc[1][1] = __builtin_amdgcn_mfma_f32_16x16x32_bf16(H1[s8], H1[s8], acc[1][1], 0,0,0);
    }
    float ib = 1.f / (*p.pbeta);
    #pragma unroll
    for (int I = 0; I < 2; I++)
      #pragma unroll
      for (int J = 0; J < 2; J++)
        #pragma unroll
        for (int r = 0; r < 4; r++) {
          int row = I*16 + quad*4 + r, col = J*16 + l15;
          p.outVar[(size_t)n*1024 + row*32 + col] = acc[I][J][r] + (row == col ? ib : 0.f);
        }
  } else if (bx < 384) {
    int rbase = (bx - 256)*8;
    int c = tid & 31, r = rbase + (tid >> 5);
    float acc = 0;
    for (int k = 0; k < 256; k += 4) {
      float4 a4 = *(const float4*)&p.psi1[r*256 + k];
      acc += a4.x*p.t3[(k+0)*32+c] + a4.y*p.t3[(k+1)*32+c]
           + a4.z*p.t3[(k+2)*32+c] + a4.w*p.t3[(k+3)*32+c];
    }
    p.outMean[r*32 + c] = acc;
  } else if (bx < 392) {
    // Wfused: M = Kinv[rows,:]@psi2s (LDS), W = M@Kinv, fold W.(Scov+qq)
    int b = bx - 384;
    int row0 = b*32;
    float* M  = sb;           // [32][257]
    float* As = sb + 8224;    // [32][33] k-major
    float* Bs = sb + 9280;    // [32][33]
    int r2 = (tid >> 4)*2, c2 = (tid & 15)*2;
    int sr = tid >> 3, sq = (tid & 7)*4;
    for (int cc = 0; cc < 256; cc += 32) {
      float a00=0, a01=0, a10=0, a11=0;
      for (int kc = 0; kc < 256; kc += 32) {
        float4 av = *(const float4*)&p.Kinv[(row0+sr)*MI + kc + sq];
        As[(sq+0)*33 + sr] = av.x; As[(sq+1)*33 + sr] = av.y;
        As[(sq+2)*33 + sr] = av.z; As[(sq+3)*33 + sr] = av.w;
        float4 bv = *(const float4*)&p.psi2s[(kc+sr)*MI + cc + sq];
        Bs[sr*33 + sq+0] = bv.x; Bs[sr*33 + sq+1] = bv.y;
        Bs[sr*33 + sq+2] = bv.z; Bs[sr*33 + sq+3] = bv.w;
        __syncthreads();
        #pragma unroll
        for (int kk = 0; kk < 32; kk++) {
          float x0 = As[kk*33 + r2], x1 = As[kk*33 + r2 + 1];
          float y0 = Bs[kk*33 + c2], y1 = Bs[kk*33 + c2 + 1];
          a00 += x0*y0; a01 += x0*y1; a10 += x1*y0; a11 += x1*y1;
        }
        __syncthreads();
      }
      M[(r2+0)*257 + cc + c2]     = a00;
      M[(r2+0)*257 + cc + c2 + 1] = a01;
      M[(r2+1)*257 + cc + c2]     = a10;
      M[(r2+1)*257 + cc + c2 + 1] = a11;
    }
    __syncthreads();
    float tacc = 0;
    for (int cc = 0; cc < 256; cc += 32) {
      float a00=0, a01=0, a10=0, a11=0;
      for (int kc = 0; kc < 256; kc += 32) {
        float4 bv = *(const float4*)&p.Kinv[(kc+sr)*MI + cc + sq];
        Bs[sr*33 + sq+0] = bv.x; Bs[sr*33 + sq+1] = bv.y;
        Bs[sr*33 + sq+2] = bv.z; Bs[sr*33 + sq+3] = bv.w;
        __syncthreads();
        #pragma unroll
        for (int kk = 0; kk < 32; kk++) {
          float x0 = M[r2*257 + kc + kk], x1 = M[(r2+1)*257 + kc + kk];
          float y0 = Bs[kk*33 + c2], y1 = Bs[kk*33 + c2 + 1];
          a00 += x0*y0; a01 += x0*y1; a10 += x1*y0; a11 += x1*y1;
        }
        __syncthreads();
      }
      float wv[2][2] = {{a00, a01}, {a10, a11}};
      #pragma unroll
      for (int i = 0; i < 2; i++)
        #pragma unroll
        for (int j = 0; j < 2; j++) {
          int R = row0 + r2 + i, C = cc + c2 + j;
          float qq = 0;
          #pragma unroll
          for (int d4 = 0; d4 < 32; d4 += 4) {
            float4 qa = *(const float4*)&p.qmu[R*32 + d4];
            float4 qb = *(const float4*)&p.qmu[C*32 + d4];
            qq += qa.x*qb.x + qa.y*qb.y + qa.z*qb.z + qa.w*qb.w;
          }
          tacc += wv[i][j]*(p.Scov[R*256 + C] + qq);
        }
    }
    BLOCK_FOLD_FIN(tacc, red, p, 6);
  } else {
    int idx = bx - 392;
    int seg = idx >> 5;
    int i0 = (idx & 31)*256 + tid;
    const int stride = 32*256;
    float s = 0;
    int target = 0;
    if (seg == 0) { for (int i = i0; i < 65536; i += stride) s += p.Kinv[i]*p.psi2s[i]; target = 0; }
    else if (seg == 1) { for (int i = i0; i < 8192; i += stride) s += p.qmu[i]*p.t3[i]; target = 1; }
    else if (seg == 2) { for (int i = i0; i < 65536; i += stride) s += p.Kinv[i]*p.Scov[i]; target = 2; }
    else if (seg == 3) {
      float invc = 1.f/(*p.pvar + JITTER);
      for (int i = i0; i < 65536; i += stride) {
        int r = i >> 8, c = i & 255;
        if (r != c) { float e = p.KM[i]*invc; s += e*e; }
      }
      target = 4;
    }
    else if (seg == 4) {
      for (int i = i0; i < MI*DOUT; i += stride) {
        int m = i >> 5, k = i & 31;
        float dq = p.qs[m*8224 + k];   // (m*256+m)*32 + k
        s += logf(dq*dq);
      }
      target = 5;
    }
    else {
      // sum GA . (Scov + qmu qmu^T)
      for (int i = i0; i < 65536; i += stride) {
        int r = i >> 8, c = i & 255;
        float qq = 0;
        #pragma unroll
        for (int d = 0; d < DOUT; d++) qq += p.qmu[r*DOUT + d]*p.qmu[c*DOUT + d];
        s += p.GA[i]*(p.Scov[i] + qq);
      }
      target = 7;
    }
    BLOCK_FOLD_FIN(s, red, p, target);
  }
}

extern "C" void kernel_launch(void* const* d_in, const int* in_sizes, int n_in,
                              void* d_out, int out_size, void* d_ws, size_t ws_size,
                              hipStream_t stream) {
  (void)in_sizes; (void)n_in; (void)out_size; (void)ws_size;
  float* out = (float*)d_out;
  float* ws  = (float*)d_ws;

  Params p;
  p.Xm = (const float*)d_in[0];
  p.Xv = (const float*)d_in[1];
  p.Z  = (const float*)d_in[2];
  p.qmu = (const float*)d_in[3];
  p.qs  = (const float*)d_in[4];
  p.ls  = (const float*)d_in[5];
  p.pvar  = (const float*)d_in[6];
  p.pbeta = (const float*)d_in[7];
  p.psi2s = ws + OFF_PSI2S;
  p.Scov  = ws + OFF_SCOV;
  p.GA    = ws + OFF_GA;
  p.Sv    = ws + OFF_S;
  p.zarea = ws;
  p.psi1  = ws + OFF_PSI1;
  p.p1h   = (ushort*)(ws + OFF_P1H);
  p.gm    = ws + OFF_GM;
  p.f2    = ws + OFF_F2;
  p.KM    = ws + OFF_KM;
  p.Kinv  = ws + OFF_KINV;
  p.Kh    = (ushort*)(ws + OFF_KH);
  p.t3    = ws + OFF_T3;
  p.zb    = (ushort*)(ws + OFF_ZB);
  p.abf   = (ushort*)(ws + OFF_ABF);
  p.abfT  = (ushort*)(ws + OFF_ABFT);
  p.Btj   = (ushort*)(ws + OFF_BTJ);
  p.Btl   = (ushort*)(ws + OFF_BTL);
  p.tmp   = (ushort*)(ws + OFF_TMP);
  p.outMean = out;
  p.outVar  = out + 32768;
  p.outL    = out + 32768 + 1048576;

  kA<<<3497, 256, 0, stream>>>(p);
  kB<<<1248, 256, 0, stream>>>(p);
  kE<<<2112, 256, 0, stream>>>(p);
  kF<<<584, 256, 0, stream>>>(p);
}